// Round 8
// baseline (217.509 us; speedup 1.0000x reference)
//
#include <hip/hip_runtime.h>
#include <cstdint>

#define IROWS 50000
#define DIM   512
#define KTOT  1024
#define THREADS 512
#define BM    128
#define NBLK ((IROWS + BM - 1) / BM)   // 391
#define NCHUNK 32
#define CK 32

typedef __bf16 bf16x8 __attribute__((ext_vector_type(8)));
typedef float  f32x4  __attribute__((ext_vector_type(4)));

// LDS: B triple-buffer 3x32KB + A double-buffer 2x8KB = 112KB -> 1 blk/CU
#define B_SZ    32768
#define A_SZ    8192
#define OFF_A   (3 * B_SZ)
#define SMEM_SZ (OFF_A + 2 * A_SZ)     // 114688
#define OFF_R1  OFF_A                  // red1[128][8][2] f32 = 8KB (epilogue overlay)
#define OFF_R2  (OFF_A + 8192)         // red2[128][8] f32 = 4KB

__device__ __forceinline__ uint16_t f2bf(float f) {
  uint32_t u = __float_as_uint(f);
  u += 0x7fffu + ((u >> 16) & 1u);   // RNE (inputs finite)
  return (uint16_t)(u >> 16);
}

// btT layout (R7-verified): element (k, n) at (k>>3)*4096 + n*8 + (k&7)
// = 128 k-planes of [512 cols][8 k] bf16; chunk c = planes 4c..4c+3 = 32KB contiguous.
__global__ __launch_bounds__(256) void prep_bt(const float* __restrict__ dimg,
                                               const float* __restrict__ dtxt,
                                               const float* __restrict__ pa,
                                               const float* __restrict__ pb,
                                               uint16_t* __restrict__ btT) {
  __shared__ uint16_t tile[64][80];
  int bid = blockIdx.x;               // 128 blocks: 16 k-tiles x 8 n-tiles
  int kt = bid >> 3, nt = bid & 7;
  int k0 = kt * 64, n0 = nt * 64;
  const float* src; float sc;
  if (k0 < 512) { src = dimg + (size_t)k0 * 512;         sc = pa[0]; }
  else          { src = dtxt + (size_t)(k0 - 512) * 512; sc = pb[0]; }
  int t = threadIdx.x;
  int c4 = (t & 15) * 4, r = t >> 4;
  for (int rr = r; rr < 64; rr += 16) {
    float4 v = *(const float4*)(src + (size_t)rr * 512 + n0 + c4);
    tile[c4 + 0][rr] = f2bf(v.x * sc);
    tile[c4 + 1][rr] = f2bf(v.y * sc);
    tile[c4 + 2][rr] = f2bf(v.z * sc);
    tile[c4 + 3][rr] = f2bf(v.w * sc);
  }
  __syncthreads();
  int nn = t >> 3, j8 = t & 7;
  for (int n2 = nn; n2 < 64; n2 += 32) {
    uint4 val = *(const uint4*)(&tile[n2][j8 * 8]);
    *(uint4*)(btT + ((size_t)((k0 >> 3) + j8)) * 4096 + (size_t)(n0 + n2) * 8) = val;
  }
}

__global__ __launch_bounds__(THREADS, 2) void fused_main(
    const float* __restrict__ zcf, const float* __restrict__ zimg,
    const float* __restrict__ ztxt, const uint16_t* __restrict__ btT,
    const float* __restrict__ pa, const float* __restrict__ pb,
    const float* __restrict__ lnw, const float* __restrict__ lnb,
    float* __restrict__ out) {
  __shared__ __align__(16) char smem[SMEM_SZ];
  const int t    = threadIdx.x;
  const int lane = t & 63;
  const int w    = t >> 6;          // wave 0..7 owns cols [w*64, w*64+64)
  const int cl   = lane & 15;
  const int kq   = lane >> 4;       // 0..3
  const int row0 = blockIdx.x * BM;

  f32x4 acc[8][4];
  const f32x4 zero = {0.f, 0.f, 0.f, 0.f};
#pragma unroll
  for (int mf = 0; mf < 8; ++mf)
#pragma unroll
    for (int nf = 0; nf < 4; ++nf) acc[mf][nf] = zero;

  // ---- A staging: thread t -> row ar = t>>2 (0..127), k-slot aks = t&3 (8 k) ----
  const int ar = t >> 2, aks = t & 3;
  const size_t arow = (size_t)min(row0 + ar, IROWS - 1) * DIM;
  auto aload = [&](int c, float4* d) {
    int gk = c * CK + aks * 8;
    const float* s = (gk < 512) ? (zimg + gk) : (ztxt + gk - 512);
    d[0] = *(const float4*)(s + arow);
    d[1] = *(const float4*)(s + arow + 4);
  };
  auto astore = [&](char* Ab, const float4* v) {
    uint4 pk;
    pk.x = (uint32_t)f2bf(v[0].x) | ((uint32_t)f2bf(v[0].y) << 16);
    pk.y = (uint32_t)f2bf(v[0].z) | ((uint32_t)f2bf(v[0].w) << 16);
    pk.z = (uint32_t)f2bf(v[1].x) | ((uint32_t)f2bf(v[1].y) << 16);
    pk.w = (uint32_t)f2bf(v[1].z) | ((uint32_t)f2bf(v[1].w) << 16);
    *(uint4*)(Ab + ar * 64 + aks * 16) = pk;   // [row][32k] bf16, linear per wave
  };
  // ---- B staging: 4 gload_lds/wave, 1KB bursts, linear (btT chunk is contiguous) ----
  auto bstage = [&](int c, char* Bb) {
#pragma unroll
    for (int i = 0; i < 4; ++i) {
      int u = w * 4 + i;            // 0..31 KB-unit
      const uint16_t* src = btT + (size_t)c * 16384 + u * 512 + lane * 8;
      char* dst = Bb + u * 1024;    // wave-uniform; HW adds lane*16
      __builtin_amdgcn_global_load_lds(
          (__attribute__((address_space(1))) unsigned int*)src,
          (__attribute__((address_space(3))) unsigned int*)dst, 16, 0, 0);
    }
  };
  auto compute = [&](const char* Bb, const char* Ab) {
    bf16x8 bf[4];
#pragma unroll
    for (int nf = 0; nf < 4; ++nf)
      bf[nf] = *(const bf16x8*)(Bb + kq * 8192 + (w * 64 + nf * 16 + cl) * 16);
    __builtin_amdgcn_s_setprio(1);
#pragma unroll
    for (int mf = 0; mf < 8; ++mf) {
      bf16x8 af = *(const bf16x8*)(Ab + (mf * 16 + cl) * 64 + kq * 16);
#pragma unroll
      for (int nf = 0; nf < 4; ++nf)
        acc[mf][nf] = __builtin_amdgcn_mfma_f32_16x16x32_bf16(af, bf[nf], acc[mf][nf], 0, 0, 0);
    }
    __builtin_amdgcn_s_setprio(0);
  };

  char* B0 = smem;            char* B1 = smem + B_SZ;   char* B2 = smem + 2 * B_SZ;
  char* A0 = smem + OFF_A;    char* A1 = smem + OFF_A + A_SZ;
  float4 S0[2], S1[2];

  // ---- prologue: establish invariant {B(c),A(c) in LDS; B(c+1)+A(c+1) in flight} ----
  aload(0, S0); bstage(0, B0);
  asm volatile("s_waitcnt vmcnt(4)" ::: "memory");   // S0 done; B0 flies
  astore(A0, S0);
  aload(1, S1); bstage(1, B1);
  asm volatile("s_waitcnt vmcnt(6)" ::: "memory");   // B0 landed; S1+B1 fly
  asm volatile("s_waitcnt lgkmcnt(0)" ::: "memory");
  __builtin_amdgcn_sched_barrier(0);
  __builtin_amdgcn_s_barrier();
  __builtin_amdgcn_sched_barrier(0);

  // BODY(c): stage c+2, wait(only last-iter objects), write A(c+1), load A(c+2),
  // compute(c). vmcnt(4) leaves the just-issued B(c+2) in flight. Never drains.
#define BODY(c, Bc, Bc2, Acur, Anxt, Snxt, Snxt2)                            \
  {                                                                          \
    bstage((c) + 2, Bc2);                                                    \
    asm volatile("s_waitcnt vmcnt(4)" ::: "memory");                         \
    __builtin_amdgcn_sched_barrier(0);                                       \
    astore(Anxt, Snxt);                                                      \
    aload((c) + 2, Snxt2);                                                   \
    compute(Bc, Acur);                                                       \
    asm volatile("s_waitcnt lgkmcnt(0)" ::: "memory");                       \
    __builtin_amdgcn_sched_barrier(0);                                       \
    __builtin_amdgcn_s_barrier();                                            \
    __builtin_amdgcn_sched_barrier(0);                                       \
  }

#pragma unroll 1
  for (int c6 = 0; c6 < 30; c6 += 6) {     // chunks 0..29, static buffer rotation
    BODY(c6 + 0, B0, B2, A0, A1, S1, S0)
    BODY(c6 + 1, B1, B0, A1, A0, S0, S1)
    BODY(c6 + 2, B2, B1, A0, A1, S1, S0)
    BODY(c6 + 3, B0, B2, A1, A0, S0, S1)
    BODY(c6 + 4, B1, B0, A0, A1, S1, S0)
    BODY(c6 + 5, B2, B1, A1, A0, S0, S1)
  }
#undef BODY
  // tail: c=30 (B0/A0), then c=31 (B1/A1)
  asm volatile("s_waitcnt vmcnt(0)" ::: "memory");   // B31 + S1 land
  __builtin_amdgcn_sched_barrier(0);
  astore(A1, S1);
  compute(B0, A0);
  asm volatile("s_waitcnt lgkmcnt(0)" ::: "memory");
  __builtin_amdgcn_sched_barrier(0);
  __builtin_amdgcn_s_barrier();
  __builtin_amdgcn_sched_barrier(0);
  compute(B1, A1);
  __syncthreads();                                   // before LDS overlay reuse

  // ---- epilogue: + wcf*z_cf, LayerNorm, L2 normalize ----
  const float wcf = 1.0f - pa[0] - pb[0];
  float (*red1)[8][2] = (float (*)[8][2])(smem + OFF_R1);   // [row][wave][{s1,s2}]
  float (*red2)[8]    = (float (*)[8])(smem + OFF_R2);      // [row][wave]

#pragma unroll
  for (int mf = 0; mf < 8; ++mf)
#pragma unroll
    for (int reg = 0; reg < 4; ++reg) {
      int row = min(row0 + mf * 16 + kq * 4 + reg, IROWS - 1);
      const float* zr = zcf + (size_t)row * DIM + w * 64 + cl;
#pragma unroll
      for (int nf = 0; nf < 4; ++nf)
        acc[mf][nf][reg] += wcf * zr[nf * 16];
    }

#pragma unroll
  for (int mf = 0; mf < 8; ++mf)
#pragma unroll
    for (int reg = 0; reg < 4; ++reg) {
      float s1 = 0.f, s2 = 0.f;
#pragma unroll
      for (int nf = 0; nf < 4; ++nf) { float v = acc[mf][nf][reg]; s1 += v; s2 += v * v; }
#pragma unroll
      for (int m = 1; m < 16; m <<= 1) { s1 += __shfl_xor(s1, m, 64); s2 += __shfl_xor(s2, m, 64); }
      if (cl == 0) {
        int rl = mf * 16 + kq * 4 + reg;
        red1[rl][w][0] = s1;
        red1[rl][w][1] = s2;
      }
    }
  __syncthreads();

  float lw[4], lb[4];
#pragma unroll
  for (int nf = 0; nf < 4; ++nf) {
    lw[nf] = lnw[w * 64 + nf * 16 + cl];
    lb[nf] = lnb[w * 64 + nf * 16 + cl];
  }

  float q[8][4];
#pragma unroll
  for (int mf = 0; mf < 8; ++mf)
#pragma unroll
    for (int reg = 0; reg < 4; ++reg) {
      int rl = mf * 16 + kq * 4 + reg;
      float s1 = 0.f, s2 = 0.f;
#pragma unroll
      for (int ww = 0; ww < 8; ++ww) { s1 += red1[rl][ww][0]; s2 += red1[rl][ww][1]; }
      float mu = s1 * (1.0f / 512.0f);
      float rs = rsqrtf(s2 * (1.0f / 512.0f) - mu * mu + 1e-5f);
      float qq = 0.f;
#pragma unroll
      for (int nf = 0; nf < 4; ++nf) {
        float y = (acc[mf][nf][reg] - mu) * rs * lw[nf] + lb[nf];
        acc[mf][nf][reg] = y;
        qq += y * y;
      }
#pragma unroll
      for (int m = 1; m < 16; m <<= 1) qq += __shfl_xor(qq, m, 64);
      if (cl == 0) red2[rl][w] = qq;
      q[mf][reg] = 0.f;   // placeholder, finalized after sync
    }
  __syncthreads();

#pragma unroll
  for (int mf = 0; mf < 8; ++mf)
#pragma unroll
    for (int reg = 0; reg < 4; ++reg) {
      int rl  = mf * 16 + kq * 4 + reg;
      int row = row0 + rl;
      float qq = 0.f;
#pragma unroll
      for (int ww = 0; ww < 8; ++ww) qq += red2[rl][ww];
      float rn = 1.0f / fmaxf(sqrtf(qq), 1e-12f);
      if (row < IROWS) {
        float* orow = out + (size_t)row * DIM + w * 64 + cl;
#pragma unroll
        for (int nf = 0; nf < 4; ++nf)
          orow[nf * 16] = acc[mf][nf][reg] * rn;
      }
      (void)q;
    }
}

extern "C" void kernel_launch(void* const* d_in, const int* in_sizes, int n_in,
                              void* d_out, int out_size, void* d_ws, size_t ws_size,
                              hipStream_t stream) {
  const float* zcf  = (const float*)d_in[0];
  const float* zimg = (const float*)d_in[1];
  const float* ztxt = (const float*)d_in[2];
  const float* dimg = (const float*)d_in[3];
  const float* dtxt = (const float*)d_in[4];
  const float* pa   = (const float*)d_in[5];
  const float* pb   = (const float*)d_in[6];
  const float* lnw  = (const float*)d_in[7];
  const float* lnb  = (const float*)d_in[8];
  uint16_t* btT = (uint16_t*)d_ws;   // 1 MB, k-plane-major bf16

  hipLaunchKernelGGL(prep_bt, dim3(128), dim3(256), 0, stream, dimg, dtxt, pa, pb, btT);
  hipLaunchKernelGGL(fused_main, dim3(NBLK), dim3(THREADS), 0, stream,
                     zcf, zimg, ztxt, btT, pa, pb, lnw, lnb, (float*)d_out);
}